// Round 8
// baseline (343.133 us; speedup 1.0000x reference)
//
#include <hip/hip_runtime.h>
#include <hip/hip_fp16.h>
#include <math.h>

// GAT 3-layer: N=50000 nodes, E=800000 edges (+N self loops), HEADS=2, HID=64.
// R29: kill the device atomics in the CSR build. R28 counters: count_rank_prep
// 57.5us @ VALU 0.3%, HBM 7% -> 800k atomicAdd-with-return at ~7/cycle device
// service rate (throughput wall, latency already 4-deep hidden). Replaced by
// partitioned LDS histogram: 8 dst-parts (6400x4B LDS) x 32 edge-chunks = 256
// blocks; per-block LDS atomics (per-CU, fast) give chunk-local rank; hist
// slices written plain. scan_blocks also does in-place exclusive prefix over
// chunks per dst (chunkbase); place adds chunkbase[chunk][dst]. Chunk-major
// slot order is a valid permutation (softmax/sum order-invariant).
// Aggregate reverted to exact R25 body (57.6us, VGPR 64) — R26/R27/R28 all
// null: the aggregate is at a random-line request-service wall (~4x64B lines
// per edge); do NOT restructure it further (only untried lever: fp8 H rows,
// accuracy-risky).
// Kept (measured optima): MFMA gemms (R22), scan_add2 fold, data-parallel
// gcnt (R25), atomic pool/finalize fold.
// DEAD ENDS (do not revisit): agg+gemm fusion (R23); single-block binary-
// search prep (R24); holding H-lines across softmax (R26); persistent grid
// (R27); dual-pair interleave (R28).

__device__ __forceinline__ float lrelu(float v) { return v > 0.f ? v : 0.2f * v; }

__device__ __forceinline__ float wave_max(float v) {
  for (int off = 32; off; off >>= 1) v = fmaxf(v, __shfl_xor(v, off, 64));
  return v;
}
__device__ __forceinline__ float half_sum(float v) {
  for (int off = 16; off; off >>= 1) v += __shfl_xor(v, off, 64);
  return v;
}
__device__ __forceinline__ float half_max(float v) {
  for (int off = 16; off; off >>= 1) v = fmaxf(v, __shfl_xor(v, off, 64));
  return v;
}

typedef _Float16 f16x8 __attribute__((ext_vector_type(8)));
typedef float f32x4 __attribute__((ext_vector_type(4)));

#define PARTSZ 6400   // dsts per LDS histogram part (25.6 KB)
#define NCHUNK 32     // edge chunks

// storage index ks (0..63) -> true column of previous layer's 64-col output
__device__ __forceinline__ int colperm(int l, int ks) {
  return l == 0 ? ks : (((ks & 3) << 4) | ((ks >> 3) << 1) | ((ks >> 2) & 1));
}

// blocks < P*C: LDS-histogram CSR prep (chunk = bx/P, part = bx%P; adjacent
// blocks share the same edge chunk -> L2/L3 reuse). Then 24 WT'-build blocks,
// then gcnt blocks (atomic float, 50k ops — cheap) + gout init.
__global__ void hist_rank_prep(const int* __restrict__ ei, int* __restrict__ rank,
                               int* __restrict__ hist, int e, int cs, int P, int C,
                               const float* __restrict__ W1, const float* __restrict__ as1,
                               const float* __restrict__ ad1,
                               const float* __restrict__ W2, const float* __restrict__ as2,
                               const float* __restrict__ ad2,
                               const float* __restrict__ W3, const float* __restrict__ as3,
                               const float* __restrict__ ad3,
                               __half* __restrict__ WT1, __half* __restrict__ WT2,
                               __half* __restrict__ WT3,
                               const int* __restrict__ batch, const float* __restrict__ lb,
                               float* __restrict__ gcnt, float* __restrict__ gout,
                               int nn, int G) {
  __shared__ int h[PARTSZ];
  int bx = blockIdx.x;
  int tid = threadIdx.x;
  int PC = P * C;
  if (bx < PC) {
    int c = bx / P;
    int part = bx - c * P;
    int d0 = part * PARTSZ;
    for (int i = tid; i < PARTSZ; i += 256) h[i] = 0;
    __syncthreads();
    int j1 = (c + 1) * cs; if (j1 > e) j1 = e;
    for (int j = c * cs + tid; j < j1; j += 256) {
      int d = ei[e + j] - d0;
      if ((unsigned)d < (unsigned)PARTSZ) rank[j] = atomicAdd(&h[d], 1);
    }
    __syncthreads();
    for (int i = tid; i < PARTSZ; i += 256) {
      int d = d0 + i;
      if (d < nn) hist[c * nn + d] = h[i];
    }
    return;
  }
  int pb = bx - PC;                       // 0..23: WT build; 24..: batch count
  if (pb >= 24) {
    int pc = pb - 24;
    if (pc == 0) {                        // gout init (nothing else writes gout)
      float lb0 = lb[0];
      for (int g = tid; g < G; g += 256) gout[g] = lb0;
    }
    int j0 = pc * 1024 + tid;
#pragma unroll
    for (int k = 0; k < 4; ++k) {
      int i = j0 + k * 256;
      if (i < nn) atomicAdd(&gcnt[batch[i]], 1.0f);
    }
    return;
  }
  int l = pb >> 3, part = pb & 7;
  const float* W = l == 0 ? W1 : (l == 1 ? W2 : W3);
  const float* as = l == 0 ? as1 : (l == 1 ? as2 : as3);
  const float* ad = l == 0 ? ad1 : (l == 1 ? ad2 : ad3);
  __half* WT = l == 0 ? WT1 : (l == 1 ? WT2 : WT3);
  const int shk = l == 0 ? 7 : 6;
  const int K = 1 << shk;
  for (int idx = part * 256 + tid; idx < 144 * K; idx += 2048) {
    int row = idx >> shk;                 // output col c' (0..127), v-rows, pad
    int ks = idx & (K - 1);               // storage k index
    int kt = colperm(l, ks);              // true input col
    float val;
    if (row < 128) {
      val = W[kt * 128 + row];
    } else if (row < 132) {
      int j = row - 128;                  // 0:src_h0 1:src_h1 2:dst_h0 3:dst_h1
      const float* att = (j < 2 ? as : ad) + (j & 1) * 64;
      const float* wr = W + kt * 128 + (j & 1) * 64;
      float acc = 0.f;
#pragma unroll
      for (int cc = 0; cc < 64; ++cc) acc = fmaf(wr[cc], att[cc], acc);
      val = acc;
    } else {
      val = 0.f;                          // pad rows of the 9th n-tile
    }
    WT[idx] = __float2half(val);
  }
}

// ---- scan: per-dst deg = sum over chunk hists (in-place exclusive prefix ->
// chunkbase), then block prefix + raw block sums (as before).
__global__ void scan_blocks(int* __restrict__ hist, int* __restrict__ row_ptr,
                            int* __restrict__ btot, int n, int C) {
  __shared__ int sm[256];
  int i = blockIdx.x * 256 + threadIdx.x;
  int deg = 0;
  if (i < n) {
    for (int c = 0; c < C; ++c) {
      int hh = hist[c * n + i];
      hist[c * n + i] = deg;              // exclusive prefix over chunks
      deg += hh;
    }
  }
  sm[threadIdx.x] = deg;
  __syncthreads();
  for (int off = 1; off < 256; off <<= 1) {
    int t = (threadIdx.x >= off) ? sm[threadIdx.x - off] : 0;
    __syncthreads();
    sm[threadIdx.x] += t;
    __syncthreads();
  }
  if (i < n) row_ptr[i] = sm[threadIdx.x] - deg;  // exclusive within block
  if (threadIdx.x == 255) btot[blockIdx.x] = sm[255];
}

// scan_totals folded in: every block scans btot[0..nb) in LDS and takes its
// own exclusive prefix. row_ptr[i] = scan + i (reserves self-loop slot 0).
__global__ void scan_add2(int* __restrict__ row_ptr, int* __restrict__ csr,
                          const int* __restrict__ btot, int n, int total, int nb) {
  __shared__ int sm[256];
  int v = (threadIdx.x < nb) ? btot[threadIdx.x] : 0;
  sm[threadIdx.x] = v;
  __syncthreads();
  for (int off = 1; off < 256; off <<= 1) {
    int t = (threadIdx.x >= off) ? sm[threadIdx.x - off] : 0;
    __syncthreads();
    sm[threadIdx.x] += t;
    __syncthreads();
  }
  int base = sm[blockIdx.x] - btot[blockIdx.x];  // exclusive prefix (broadcast)
  int i = blockIdx.x * 256 + threadIdx.x;
  if (i < n) {
    int v2 = row_ptr[i] + base + i;
    row_ptr[i] = v2;
    csr[v2] = i;                        // self loop
  }
  if (i == 0) row_ptr[n] = total;
}

// no atomics: slot = row_ptr[dst] + 1 + chunkbase[chunk][dst] + rank[j].
__global__ void place_kernel(const int* __restrict__ ei, const int* __restrict__ rank,
                             const int* __restrict__ row_ptr,
                             const int* __restrict__ hist, int* __restrict__ csr,
                             int e, int cs, int n) {
  int j0 = blockIdx.x * 1024 + threadIdx.x;
#pragma unroll
  for (int k = 0; k < 4; ++k) {
    int j = j0 + k * 256;
    if (j < e) {
      int d = ei[e + j];
      int c = j / cs;
      csr[row_ptr[d] + 1 + hist[c * n + d] + rank[j]] = ei[j];
    }
  }
}

// ---- MFMA gemm: block = 64 rows x 128 cols (+attn tile), 4 waves x 16 rows.
// A-frag: lane reads Al[row=l&15][k=(l>>4)*8 + 32*ks]. B-frag: Wl[16n+(l&15)].
// D: col=l&15, row=(l>>4)*4+reg. n=0..3 head0, 4..7 head1, 8 folded attention.
template <int K, bool F16IN>
__global__ __launch_bounds__(256) void gemm_mfma(const void* __restrict__ Xv,
                                                 const __half* __restrict__ WT,
                                                 __half* __restrict__ H16,
                                                 float* __restrict__ a_src,
                                                 float* __restrict__ a_dst, int N) {
  constexpr int KP = K + 8;               // +16B pad: ds_read_b128 2-way banks
  extern __shared__ __half smem[];
  __half* Al = smem;                      // [64][KP]
  __half* Wl = smem + 64 * KP;            // [144][KP]
  int tid = threadIdx.x;
  int row0 = blockIdx.x * 64;

  if constexpr (F16IN) {
    const __half* X = (const __half*)Xv;
    constexpr int CH = K / 8;
    for (int idx = tid; idx < 64 * CH; idx += 256) {
      int r = idx / CH, ch = idx % CH;
      int gr = row0 + r; if (gr >= N) gr = N - 1;
      *(uint4*)&Al[r * KP + ch * 8] = *(const uint4*)(X + (size_t)gr * K + ch * 8);
    }
  } else {
    const float* X = (const float*)Xv;
    constexpr int CH4 = K / 4;
    for (int idx = tid; idx < 64 * CH4; idx += 256) {
      int r = idx / CH4, ch = idx % CH4;
      int gr = row0 + r; if (gr >= N) gr = N - 1;
      float4 v = *(const float4*)(X + (size_t)gr * K + ch * 4);
      union { __half2 h2[2]; uint2 u; } t;
      t.h2[0] = __floats2half2_rn(v.x, v.y);
      t.h2[1] = __floats2half2_rn(v.z, v.w);
      *(uint2*)&Al[r * KP + ch * 4] = t.u;
    }
  }
  constexpr int CHW = K / 8;
  for (int idx = tid; idx < 144 * CHW; idx += 256) {
    int r = idx / CHW, ch = idx % CHW;
    *(uint4*)&Wl[r * KP + ch * 8] = *(const uint4*)(WT + r * K + ch * 8);
  }
  __syncthreads();

  int lane = tid & 63;
  int wv = tid >> 6;
  int q = lane & 15;
  int kg = lane >> 4;

  f32x4 acc[9] = {};
  const __half* ap = &Al[(wv * 16 + q) * KP + kg * 8];
  const __half* wp = &Wl[q * KP + kg * 8];
#pragma unroll
  for (int ks = 0; ks < K / 32; ++ks) {
    f16x8 a = *(const f16x8*)(ap + ks * 32);
#pragma unroll
    for (int n = 0; n < 9; ++n) {
      f16x8 b = *(const f16x8*)(wp + n * 16 * KP + ks * 32);
      acc[n] = __builtin_amdgcn_mfma_f32_16x16x32_f16(a, b, acc[n], 0, 0, 0);
    }
  }

#pragma unroll
  for (int reg = 0; reg < 4; ++reg) {
    int r = row0 + wv * 16 + kg * 4 + reg;
    if (r < N) {
      union { __half2 h2[2]; uint2 u; } s0, s1;
      s0.h2[0] = __floats2half2_rn(acc[0][reg], acc[1][reg]);
      s0.h2[1] = __floats2half2_rn(acc[2][reg], acc[3][reg]);
      s1.h2[0] = __floats2half2_rn(acc[4][reg], acc[5][reg]);
      s1.h2[1] = __floats2half2_rn(acc[6][reg], acc[7][reg]);
      // interleaved layout: half index = h*64 + q*4 + n_h
      *(uint2*)(H16 + (size_t)r * 128 + q * 4) = s0.u;
      *(uint2*)(H16 + (size_t)r * 128 + 64 + q * 4) = s1.u;
      float av = acc[8][reg];             // folded attention tile
      if (q < 2) a_src[r * 2 + q] = av;
      else if (q < 4) a_dst[r * 2 + q - 2] = av;
    }
  }
}

// ---- 2-edges-per-load gather ----
__device__ __forceinline__ void ld_grp8(const __half* __restrict__ H16, int half_,
                                        int c8, int headsel, int sub, int s,
                                        float p0, float p1, int g,
                                        uint4* h, float* q) {
#pragma unroll
  for (int k = 0; k < 4; ++k) {
    int idx = half_ + g * 8 + k * 2 + sub;   // e <= 31 always (g<=3)
    int st = __shfl(s, idx, 64);
    float q0 = __shfl(p0, idx, 64);
    float q1 = __shfl(p1, idx, 64);
    q[k] = headsel ? q1 : q0;
    h[k] = *(const uint4*)(H16 + (size_t)st * 128 + c8);
  }
}
__device__ __forceinline__ void fma_grp8(const uint4* h, const float* q,
                                         float* acc) {
#pragma unroll
  for (int k = 0; k < 4; ++k) {
    union { uint u; __half2 h2; } a, b, c, d;
    a.u = h[k].x; b.u = h[k].y; c.u = h[k].z; d.u = h[k].w;
    float2 f0 = __half22float2(a.h2);
    float2 f1 = __half22float2(b.h2);
    float2 f2 = __half22float2(c.h2);
    float2 f3 = __half22float2(d.h2);
    acc[0] = fmaf(f0.x, q[k], acc[0]);
    acc[1] = fmaf(f0.y, q[k], acc[1]);
    acc[2] = fmaf(f1.x, q[k], acc[2]);
    acc[3] = fmaf(f1.y, q[k], acc[3]);
    acc[4] = fmaf(f2.x, q[k], acc[4]);
    acc[5] = fmaf(f2.y, q[k], acc[5]);
    acc[6] = fmaf(f3.x, q[k], acc[6]);
    acc[7] = fmaf(f3.y, q[k], acc[7]);
  }
}
__device__ __forceinline__ void gather_pipe8(const __half* __restrict__ H16, int half_,
                                             int c8, int headsel, int sub, int s,
                                             float p0, float p1, int maxcnt,
                                             float* acc) {
  int groups = (maxcnt + 7) >> 3;   // 1..4 per 32-chunk
  uint4 ha[4], hb[4];
  float qa[4], qb[4];
  ld_grp8(H16, half_, c8, headsel, sub, s, p0, p1, 0, ha, qa);
  int g = 1;
  for (; g + 1 < groups; g += 2) {
    ld_grp8(H16, half_, c8, headsel, sub, s, p0, p1, g, hb, qb);
    fma_grp8(ha, qa, acc);
    ld_grp8(H16, half_, c8, headsel, sub, s, p0, p1, g + 1, ha, qa);
    fma_grp8(hb, qb, acc);
  }
  if (g < groups) {
    ld_grp8(H16, half_, c8, headsel, sub, s, p0, p1, g, hb, qb);
    fma_grp8(ha, qa, acc);
    fma_grp8(hb, qb, acc);
  } else {
    fma_grp8(ha, qa, acc);
  }
}

// Fused softmax + aggregate (exact R25 body). 2 dsts/wave; 2 edges per load.
// POOL=0: fp16 out rows (storage s = m*8+j, true col = colperm).
// POOL=1: pv / gcnt[bg] atomically accumulated into gout[batch[dst]].
template <int POOL>
__global__ __launch_bounds__(256) void aggregate_fused(
    const __half* __restrict__ H16, const float* __restrict__ a_src,
    const float* __restrict__ a_dst, const float* __restrict__ bias,
    const int* __restrict__ row_ptr, const int* __restrict__ csr,
    __half* __restrict__ out, const float* __restrict__ lw,
    const int* __restrict__ batch, const float* __restrict__ gcnt,
    float* __restrict__ gout, int N) {
  int lane = threadIdx.x & 63;
  int half_ = lane & 32;
  int l32 = lane & 31;
  int dst = blockIdx.x * 8 + ((threadIdx.x >> 6) << 1) + (half_ >> 5);
  bool live = dst < N;
  int beg = live ? row_ptr[dst] : 0;
  int end = live ? row_ptr[dst + 1] : 0;
  int cnt = end - beg;
  float2 ad = live ? ((const float2*)a_dst)[dst] : make_float2(0.f, 0.f);
  int sub = l32 >> 4;                   // edge-of-pair
  int m = l32 & 15;                     // 16B group index
  int c8 = m * 8;                       // halves offset (16B)
  int headsel = m >> 3;                 // m<8: head0 bytes, m>=8: head1
  float acc[8] = {};
  float inv0, inv1;

  int maxcnt = (int)wave_max((float)cnt);
  if (maxcnt < 1) maxcnt = 1;

  if (maxcnt <= 32) {
    // ---- fast path: single 32-chunk per half ----
    int j = beg + l32;
    bool valid = l32 < cnt;
    int s = valid ? csr[j] : 0;
    float2 as = ((const float2*)a_src)[s];
    float e0 = valid ? lrelu(as.x + ad.x) : -1e30f;
    float e1 = valid ? lrelu(as.y + ad.y) : -1e30f;
    float m0 = half_max(e0);
    float m1 = half_max(e1);
    float p0 = __expf(e0 - m0);         // 0 for invalid lanes
    float p1 = __expf(e1 - m1);
    inv0 = 1.f / fmaxf(half_sum(valid ? p0 : 0.f), 1e-16f);
    inv1 = 1.f / fmaxf(half_sum(valid ? p1 : 0.f), 1e-16f);
    gather_pipe8(H16, half_, c8, headsel, sub, s, p0, p1, maxcnt, acc);
  } else {
    // ---- generic path: online softmax over 32-edge chunks per half ----
    float m0 = -1e30f, m1 = -1e30f, s0 = 0.f, s1 = 0.f;
    for (int base = 0; base < maxcnt; base += 32) {
      int j = beg + base + l32;
      bool valid = (base + l32) < cnt;
      int s = valid ? csr[j] : 0;
      float2 as = ((const float2*)a_src)[s];
      float e0 = valid ? lrelu(as.x + ad.x) : -1e30f;
      float e1 = valid ? lrelu(as.y + ad.y) : -1e30f;
      float nm0 = fmaxf(m0, half_max(e0));
      float nm1 = fmaxf(m1, half_max(e1));
      s0 = s0 * __expf(m0 - nm0) + half_sum(valid ? __expf(e0 - nm0) : 0.f);
      s1 = s1 * __expf(m1 - nm1) + half_sum(valid ? __expf(e1 - nm1) : 0.f);
      m0 = nm0; m1 = nm1;
    }
    inv0 = 1.f / fmaxf(s0, 1e-16f);
    inv1 = 1.f / fmaxf(s1, 1e-16f);
    for (int base = 0; base < maxcnt; base += 32) {
      int j = beg + base + l32;
      bool valid = (base + l32) < cnt;
      int s = valid ? csr[j] : 0;
      float2 as = ((const float2*)a_src)[s];
      float e0 = valid ? lrelu(as.x + ad.x) : -1e30f;
      float e1 = valid ? lrelu(as.y + ad.y) : -1e30f;
      float p0 = __expf(e0 - m0);       // 0 invalid
      float p1 = __expf(e1 - m1);
      int rem = maxcnt - base;
      if (rem > 32) rem = 32;
      gather_pipe8(H16, half_, c8, headsel, sub, s, p0, p1, rem, acc);
    }
  }

  // combine edge-of-pair partials: lanes sub=0/1 hold different edge subsets
#pragma unroll
  for (int j = 0; j < 8; ++j) acc[j] += __shfl_xor(acc[j], 16, 64);

  float il = headsel ? inv1 : inv0;
  float v[8], w[8];
#pragma unroll
  for (int j = 0; j < 8; ++j) v[j] = acc[j] * il;
#pragma unroll
  for (int j = 0; j < 8; ++j) w[j] = __shfl_xor(v[j], 8, 64);  // head pair

  if (m < 8 && sub == 0 && live) {
    int cb = m << 1;
    float r[8];
#pragma unroll
    for (int j = 0; j < 8; ++j) {
      int c = ((j & 3) << 4) + cb + (j >> 2);   // true col (head0 decode)
      r[j] = fmaxf(0.5f * (v[j] + w[j]) + bias[c], 0.f);
    }
    if (POOL) {
      float pv = 0.f;
#pragma unroll
      for (int j = 0; j < 8; ++j) {
        int c = ((j & 3) << 4) + cb + (j >> 2);
        pv = fmaf(r[j], lw[c], pv);
      }
      pv += __shfl_xor(pv, 1, 64);
      pv += __shfl_xor(pv, 2, 64);
      pv += __shfl_xor(pv, 4, 64);
      if (m == 0) {
        int bg = batch[dst];
        atomicAdd(&gout[bg], pv / fmaxf(gcnt[bg], 1.f));
      }
    } else {
      union { __half2 h2[4]; uint4 u; } pk;
      pk.h2[0] = __floats2half2_rn(r[0], r[1]);
      pk.h2[1] = __floats2half2_rn(r[2], r[3]);
      pk.h2[2] = __floats2half2_rn(r[4], r[5]);
      pk.h2[3] = __floats2half2_rn(r[6], r[7]);
      *(uint4*)(out + (size_t)dst * 64 + m * 8) = pk.u;   // storage s = m*8+j
    }
  }
}

extern "C" void kernel_launch(void* const* d_in, const int* in_sizes, int n_in,
                              void* d_out, int out_size, void* d_ws, size_t ws_size,
                              hipStream_t stream) {
  const float* x   = (const float*)d_in[0];
  const int* ei    = (const int*)d_in[1];
  const int* batch = (const int*)d_in[2];
  const float* W1  = (const float*)d_in[3];
  const float* as1 = (const float*)d_in[4];
  const float* ad1 = (const float*)d_in[5];
  const float* b1  = (const float*)d_in[6];
  const float* W2  = (const float*)d_in[7];
  const float* as2 = (const float*)d_in[8];
  const float* ad2 = (const float*)d_in[9];
  const float* b2  = (const float*)d_in[10];
  const float* W3  = (const float*)d_in[11];
  const float* as3 = (const float*)d_in[12];
  const float* ad3 = (const float*)d_in[13];
  const float* b3  = (const float*)d_in[14];
  const float* lw  = (const float*)d_in[15];
  const float* lb  = (const float*)d_in[16];
  float* out = (float*)d_out;

  const int N = in_sizes[0] / 128;   // 50000
  const int E = in_sizes[1] / 2;     // 800000
  const int ET = N + E;              // with self loops
  const int G = out_size;            // 2500
  const int NB = (N + 255) / 256;    // scan blocks (196 <= 256)
  const int EB = (E + 1023) / 1024;  // place blocks
  const int CB = (N + 1023) / 1024;  // batch-count blocks (49)
  const int P  = (N + PARTSZ - 1) / PARTSZ;      // 8 dst parts
  const int CS = (E + NCHUNK - 1) / NCHUNK;      // 25000 edges per chunk

  char* p = (char*)d_ws;
  auto take = [&](size_t bytes) {
    char* r = p;
    p += (bytes + 255) & ~(size_t)255;
    return r;
  };
  float* gcnt   = (float*)take((size_t)G * 4);
  int* row_ptr  = (int*)take((size_t)(N + 1) * 4);
  int* rank     = (int*)take((size_t)E * 4);
  int* btot     = (int*)take((size_t)NB * 4);
  int* csr      = (int*)take((size_t)ET * 4);
  int* hist     = (int*)take((size_t)NCHUNK * N * 4);   // 6.4 MB
  __half* H16   = (__half*)take((size_t)N * 128 * 2);
  float* a_src  = (float*)take((size_t)N * 2 * 4);
  float* a_dst  = (float*)take((size_t)N * 2 * 4);
  __half* bufA  = (__half*)take((size_t)N * 64 * 2);
  __half* bufB  = (__half*)take((size_t)N * 64 * 2);
  __half* WT1   = (__half*)take((size_t)144 * 128 * 2);
  __half* WT2   = (__half*)take((size_t)144 * 64 * 2);
  __half* WT3   = (__half*)take((size_t)144 * 64 * 2);
  (void)ws_size; (void)n_in;

  // ---- CSR build (LDS histograms, no device atomics) + WT/gcnt prep ----
  hipMemsetAsync(gcnt, 0, (size_t)G * 4, stream);
  hist_rank_prep<<<P * NCHUNK + 24 + CB, 256, 0, stream>>>(
      ei, rank, hist, E, CS, P, NCHUNK,
      W1, as1, ad1, W2, as2, ad2, W3, as3, ad3, WT1, WT2, WT3,
      batch, lb, gcnt, out, N, G);
  scan_blocks<<<NB, 256, 0, stream>>>(hist, row_ptr, btot, N, NCHUNK);
  scan_add2<<<NB, 256, 0, stream>>>(row_ptr, csr, btot, N, ET, NB);
  place_kernel<<<EB, 256, 0, stream>>>(ei, rank, row_ptr, hist, csr, E, CS, N);

  const int gblk = (N + 63) / 64;           // 782
  const int ablk = (N + 7) / 8;             // 8 dsts per block (2 per wave)
  constexpr int LDS1 = (64 + 144) * (128 + 8) * 2;   // 56576 B
  constexpr int LDS2 = (64 + 144) * (64 + 8) * 2;    // 29952 B

  // ---- layer 1 (K=128, fp32 in) ----
  gemm_mfma<128, false><<<gblk, 256, LDS1, stream>>>(x, WT1, H16, a_src, a_dst, N);
  aggregate_fused<0><<<ablk, 256, 0, stream>>>(H16, a_src, a_dst, b1, row_ptr, csr,
                                               bufA, lw, batch, gcnt, out, N);
  // ---- layer 2 (K=64, fp16 in) ----
  gemm_mfma<64, true><<<gblk, 256, LDS2, stream>>>(bufA, WT2, H16, a_src, a_dst, N);
  aggregate_fused<0><<<ablk, 256, 0, stream>>>(H16, a_src, a_dst, b2, row_ptr, csr,
                                               bufB, lw, batch, gcnt, out, N);
  // ---- layer 3 (K=64, fp16 in) + fused pool/finalize ----
  gemm_mfma<64, true><<<gblk, 256, LDS2, stream>>>(bufB, WT3, H16, a_src, a_dst, N);
  aggregate_fused<1><<<ablk, 256, 0, stream>>>(H16, a_src, a_dst, b3, row_ptr, csr,
                                               bufA, lw, batch, gcnt, out, N);
}

// Round 9
// 305.053 us; speedup vs baseline: 1.1248x; 1.1248x over previous
//
#include <hip/hip_runtime.h>
#include <hip/hip_fp16.h>
#include <math.h>

// GAT 3-layer: N=50000 nodes, E=800000 edges (+N self loops), HEADS=2, HID=64.
// R30: revert to R22 exactly (best measured, 308.8us; R24/R25 dispatch-folds
// measured net -8.5us WORSE, R29 hist rewrite -34us) + ONE isolated change:
// deg counters spread 1-per-64B-line (deg[d<<4]). count_rank_prep is 57us @
// VALUBusy 0.3% / HBM 7% / occ 28% -- no pipe busy; block-lifetime math says
// latency alone = ~6us. Diagnosis: same-line L2 RMW serialization (16
// counters/line x ~16 adds = ~256 serial RMWs/line). Spreading cuts it 16x.
// NOTE: Round-1 counter table was stale (contained gemm_att from R21) -- the
// "<44us aggregate" belief was wrong; aggregate is ~58us at the random-64B
// line wall (84MB @ 1.45TB/s random-granule BW). Aggregate is CLOSED: R26
// (early-issue), R27 (persistent), R28 (dual-pair) all null.
// DEAD ENDS (do not revisit): agg+gemm fusion (R23); single-block binary-
// search prep (R24); holding H-lines across softmax (R26); persistent grid
// (R27); dual-pair interleave (R28); partitioned hist CSR (R29); scan/finalize
// folds (R24/R25: net negative vs R22).

__device__ __forceinline__ float lrelu(float v) { return v > 0.f ? v : 0.2f * v; }

__device__ __forceinline__ float wave_max(float v) {
  for (int off = 32; off; off >>= 1) v = fmaxf(v, __shfl_xor(v, off, 64));
  return v;
}
__device__ __forceinline__ float half_sum(float v) {
  for (int off = 16; off; off >>= 1) v += __shfl_xor(v, off, 64);
  return v;
}
__device__ __forceinline__ float half_max(float v) {
  for (int off = 16; off; off >>= 1) v = fmaxf(v, __shfl_xor(v, off, 64));
  return v;
}

typedef _Float16 f16x8 __attribute__((ext_vector_type(8)));
typedef float f32x4 __attribute__((ext_vector_type(4)));

// storage index ks (0..63) -> true column of previous layer's 64-col output
__device__ __forceinline__ int colperm(int l, int ks) {
  return l == 0 ? ks : (((ks & 3) << 4) | ((ks >> 3) << 1) | ((ks >> 2) & 1));
}

// rank[j] = 0-based arrival order within dst; deg counters spread 1/line
// (index d<<4) to kill same-line RMW serialization. blocks >= eb: WT' build.
__global__ void count_rank_prep(const int* __restrict__ ei, int* __restrict__ deg,
                                int* __restrict__ rank, int e, int eb,
                                const float* __restrict__ W1, const float* __restrict__ as1,
                                const float* __restrict__ ad1,
                                const float* __restrict__ W2, const float* __restrict__ as2,
                                const float* __restrict__ ad2,
                                const float* __restrict__ W3, const float* __restrict__ as3,
                                const float* __restrict__ ad3,
                                __half* __restrict__ WT1, __half* __restrict__ WT2,
                                __half* __restrict__ WT3) {
  int bx = blockIdx.x;
  if (bx < eb) {
    int j0 = bx * 1024 + threadIdx.x;
#pragma unroll
    for (int k = 0; k < 4; ++k) {
      int j = j0 + k * 256;
      if (j < e) rank[j] = atomicAdd(&deg[ei[e + j] << 4], 1);
    }
    return;
  }
  int pb = bx - eb;                       // 0..23
  int l = pb >> 3, part = pb & 7;
  const float* W = l == 0 ? W1 : (l == 1 ? W2 : W3);
  const float* as = l == 0 ? as1 : (l == 1 ? as2 : as3);
  const float* ad = l == 0 ? ad1 : (l == 1 ? ad2 : ad3);
  __half* WT = l == 0 ? WT1 : (l == 1 ? WT2 : WT3);
  const int shk = l == 0 ? 7 : 6;
  const int K = 1 << shk;
  for (int idx = part * 256 + threadIdx.x; idx < 144 * K; idx += 2048) {
    int row = idx >> shk;                 // output col c' (0..127), v-rows, pad
    int ks = idx & (K - 1);               // storage k index
    int kt = colperm(l, ks);              // true input col
    float val;
    if (row < 128) {
      val = W[kt * 128 + row];
    } else if (row < 132) {
      int j = row - 128;                  // 0:src_h0 1:src_h1 2:dst_h0 3:dst_h1
      const float* att = (j < 2 ? as : ad) + (j & 1) * 64;
      const float* wr = W + kt * 128 + (j & 1) * 64;
      float acc = 0.f;
#pragma unroll
      for (int c = 0; c < 64; ++c) acc = fmaf(wr[c], att[c], acc);
      val = acc;
    } else {
      val = 0.f;                          // pad rows of the 9th n-tile
    }
    WT[idx] = __float2half(val);
  }
}

// ---- hierarchical exclusive scan over deg (spread layout, counts only) ----
__global__ void scan_blocks(const int* __restrict__ deg, int* __restrict__ row_ptr,
                            int* __restrict__ btot, int n) {
  __shared__ int sm[256];
  int i = blockIdx.x * 256 + threadIdx.x;
  int v = (i < n) ? deg[i << 4] : 0;
  sm[threadIdx.x] = v;
  __syncthreads();
  for (int off = 1; off < 256; off <<= 1) {
    int t = (threadIdx.x >= off) ? sm[threadIdx.x - off] : 0;
    __syncthreads();
    sm[threadIdx.x] += t;
    __syncthreads();
  }
  if (i < n) row_ptr[i] = sm[threadIdx.x] - v;   // exclusive within block
  if (threadIdx.x == 255) btot[blockIdx.x] = sm[255];
}

__global__ void scan_totals(int* __restrict__ btot, int nb) {  // nb <= 256
  __shared__ int sm[256];
  int v = (threadIdx.x < nb) ? btot[threadIdx.x] : 0;
  sm[threadIdx.x] = v;
  __syncthreads();
  for (int off = 1; off < 256; off <<= 1) {
    int t = (threadIdx.x >= off) ? sm[threadIdx.x - off] : 0;
    __syncthreads();
    sm[threadIdx.x] += t;
    __syncthreads();
  }
  if (threadIdx.x < nb) btot[threadIdx.x] = sm[threadIdx.x] - v;  // exclusive
}

// row_ptr[i] = scan(counts) + i (reserves self-loop slot 0); drop self loop.
__global__ void scan_add(int* __restrict__ row_ptr, int* __restrict__ csr,
                         const int* __restrict__ btot, int n, int total) {
  int i = blockIdx.x * 256 + threadIdx.x;
  if (i < n) {
    int v = row_ptr[i] + btot[blockIdx.x] + i;
    row_ptr[i] = v;
    csr[v] = i;                         // self loop
  }
  if (i == 0) row_ptr[n] = total;
}

// no atomics: slot = row_ptr[dst] + 1 + rank. 4 independent edges per thread.
__global__ void place_kernel(const int* __restrict__ ei, const int* __restrict__ rank,
                             const int* __restrict__ row_ptr, int* __restrict__ csr,
                             int e) {
  int j0 = blockIdx.x * 1024 + threadIdx.x;
#pragma unroll
  for (int k = 0; k < 4; ++k) {
    int j = j0 + k * 256;
    if (j < e) {
      int d = ei[e + j];
      csr[row_ptr[d] + 1 + rank[j]] = ei[j];
    }
  }
}

// ---- MFMA gemm: block = 64 rows x 128 cols (+attn tile), 4 waves x 16 rows.
// A-frag: lane reads Al[row=l&15][k=(l>>4)*8 + 32*ks]. B-frag: Wl[16n+(l&15)].
// D: col=l&15, row=(l>>4)*4+reg. n=0..3 head0, 4..7 head1, 8 folded attention.
template <int K, bool F16IN>
__global__ __launch_bounds__(256) void gemm_mfma(const void* __restrict__ Xv,
                                                 const __half* __restrict__ WT,
                                                 __half* __restrict__ H16,
                                                 float* __restrict__ a_src,
                                                 float* __restrict__ a_dst, int N) {
  constexpr int KP = K + 8;               // +16B pad: ds_read_b128 2-way banks
  extern __shared__ __half smem[];
  __half* Al = smem;                      // [64][KP]
  __half* Wl = smem + 64 * KP;            // [144][KP]
  int tid = threadIdx.x;
  int row0 = blockIdx.x * 64;

  if constexpr (F16IN) {
    const __half* X = (const __half*)Xv;
    constexpr int CH = K / 8;
    for (int idx = tid; idx < 64 * CH; idx += 256) {
      int r = idx / CH, ch = idx % CH;
      int gr = row0 + r; if (gr >= N) gr = N - 1;
      *(uint4*)&Al[r * KP + ch * 8] = *(const uint4*)(X + (size_t)gr * K + ch * 8);
    }
  } else {
    const float* X = (const float*)Xv;
    constexpr int CH4 = K / 4;
    for (int idx = tid; idx < 64 * CH4; idx += 256) {
      int r = idx / CH4, ch = idx % CH4;
      int gr = row0 + r; if (gr >= N) gr = N - 1;
      float4 v = *(const float4*)(X + (size_t)gr * K + ch * 4);
      union { __half2 h2[2]; uint2 u; } t;
      t.h2[0] = __floats2half2_rn(v.x, v.y);
      t.h2[1] = __floats2half2_rn(v.z, v.w);
      *(uint2*)&Al[r * KP + ch * 4] = t.u;
    }
  }
  constexpr int CHW = K / 8;
  for (int idx = tid; idx < 144 * CHW; idx += 256) {
    int r = idx / CHW, ch = idx % CHW;
    *(uint4*)&Wl[r * KP + ch * 8] = *(const uint4*)(WT + r * K + ch * 8);
  }
  __syncthreads();

  int lane = tid & 63;
  int wv = tid >> 6;
  int q = lane & 15;
  int kg = lane >> 4;

  f32x4 acc[9] = {};
  const __half* ap = &Al[(wv * 16 + q) * KP + kg * 8];
  const __half* wp = &Wl[q * KP + kg * 8];
#pragma unroll
  for (int ks = 0; ks < K / 32; ++ks) {
    f16x8 a = *(const f16x8*)(ap + ks * 32);
#pragma unroll
    for (int n = 0; n < 9; ++n) {
      f16x8 b = *(const f16x8*)(wp + n * 16 * KP + ks * 32);
      acc[n] = __builtin_amdgcn_mfma_f32_16x16x32_f16(a, b, acc[n], 0, 0, 0);
    }
  }

#pragma unroll
  for (int reg = 0; reg < 4; ++reg) {
    int r = row0 + wv * 16 + kg * 4 + reg;
    if (r < N) {
      union { __half2 h2[2]; uint2 u; } s0, s1;
      s0.h2[0] = __floats2half2_rn(acc[0][reg], acc[1][reg]);
      s0.h2[1] = __floats2half2_rn(acc[2][reg], acc[3][reg]);
      s1.h2[0] = __floats2half2_rn(acc[4][reg], acc[5][reg]);
      s1.h2[1] = __floats2half2_rn(acc[6][reg], acc[7][reg]);
      // interleaved layout: half index = h*64 + q*4 + n_h
      *(uint2*)(H16 + (size_t)r * 128 + q * 4) = s0.u;
      *(uint2*)(H16 + (size_t)r * 128 + 64 + q * 4) = s1.u;
      float av = acc[8][reg];             // folded attention tile
      if (q < 2) a_src[r * 2 + q] = av;
      else if (q < 4) a_dst[r * 2 + q - 2] = av;
    }
  }
}

// ---- 2-edges-per-load gather ----
__device__ __forceinline__ void ld_grp8(const __half* __restrict__ H16, int half_,
                                        int c8, int headsel, int sub, int s,
                                        float p0, float p1, int g,
                                        uint4* h, float* q) {
#pragma unroll
  for (int k = 0; k < 4; ++k) {
    int idx = half_ + g * 8 + k * 2 + sub;   // e <= 31 always (g<=3)
    int st = __shfl(s, idx, 64);
    float q0 = __shfl(p0, idx, 64);
    float q1 = __shfl(p1, idx, 64);
    q[k] = headsel ? q1 : q0;
    h[k] = *(const uint4*)(H16 + (size_t)st * 128 + c8);
  }
}
__device__ __forceinline__ void fma_grp8(const uint4* h, const float* q,
                                         float* acc) {
#pragma unroll
  for (int k = 0; k < 4; ++k) {
    union { uint u; __half2 h2; } a, b, c, d;
    a.u = h[k].x; b.u = h[k].y; c.u = h[k].z; d.u = h[k].w;
    float2 f0 = __half22float2(a.h2);
    float2 f1 = __half22float2(b.h2);
    float2 f2 = __half22float2(c.h2);
    float2 f3 = __half22float2(d.h2);
    acc[0] = fmaf(f0.x, q[k], acc[0]);
    acc[1] = fmaf(f0.y, q[k], acc[1]);
    acc[2] = fmaf(f1.x, q[k], acc[2]);
    acc[3] = fmaf(f1.y, q[k], acc[3]);
    acc[4] = fmaf(f2.x, q[k], acc[4]);
    acc[5] = fmaf(f2.y, q[k], acc[5]);
    acc[6] = fmaf(f3.x, q[k], acc[6]);
    acc[7] = fmaf(f3.y, q[k], acc[7]);
  }
}
__device__ __forceinline__ void gather_pipe8(const __half* __restrict__ H16, int half_,
                                             int c8, int headsel, int sub, int s,
                                             float p0, float p1, int maxcnt,
                                             float* acc) {
  int groups = (maxcnt + 7) >> 3;   // 1..4 per 32-chunk
  uint4 ha[4], hb[4];
  float qa[4], qb[4];
  ld_grp8(H16, half_, c8, headsel, sub, s, p0, p1, 0, ha, qa);
  int g = 1;
  for (; g + 1 < groups; g += 2) {
    ld_grp8(H16, half_, c8, headsel, sub, s, p0, p1, g, hb, qb);
    fma_grp8(ha, qa, acc);
    ld_grp8(H16, half_, c8, headsel, sub, s, p0, p1, g + 1, ha, qa);
    fma_grp8(hb, qb, acc);
  }
  if (g < groups) {
    ld_grp8(H16, half_, c8, headsel, sub, s, p0, p1, g, hb, qb);
    fma_grp8(ha, qa, acc);
    fma_grp8(hb, qb, acc);
  } else {
    fma_grp8(ha, qa, acc);
  }
}

// Fused softmax + aggregate. 2 dsts/wave; 2 edges per load instruction.
// POOL=0: fp16 out rows (storage s = m*8+j, true col = colperm). POOL=1: pv.
template <int POOL>
__global__ __launch_bounds__(256) void aggregate_fused(
    const __half* __restrict__ H16, const float* __restrict__ a_src,
    const float* __restrict__ a_dst, const float* __restrict__ bias,
    const int* __restrict__ row_ptr, const int* __restrict__ csr,
    __half* __restrict__ out, const float* __restrict__ lw,
    float* __restrict__ pvn, int N) {
  int lane = threadIdx.x & 63;
  int half_ = lane & 32;
  int l32 = lane & 31;
  int dst = blockIdx.x * 8 + ((threadIdx.x >> 6) << 1) + (half_ >> 5);
  bool live = dst < N;
  int beg = live ? row_ptr[dst] : 0;
  int end = live ? row_ptr[dst + 1] : 0;
  int cnt = end - beg;
  float2 ad = live ? ((const float2*)a_dst)[dst] : make_float2(0.f, 0.f);
  int sub = l32 >> 4;                   // edge-of-pair
  int m = l32 & 15;                     // 16B group index
  int c8 = m * 8;                       // halves offset (16B)
  int headsel = m >> 3;                 // m<8: head0 bytes, m>=8: head1
  float acc[8] = {};
  float inv0, inv1;

  int maxcnt = (int)wave_max((float)cnt);
  if (maxcnt < 1) maxcnt = 1;

  if (maxcnt <= 32) {
    // ---- fast path: single 32-chunk per half ----
    int j = beg + l32;
    bool valid = l32 < cnt;
    int s = valid ? csr[j] : 0;
    float2 as = ((const float2*)a_src)[s];
    float e0 = valid ? lrelu(as.x + ad.x) : -1e30f;
    float e1 = valid ? lrelu(as.y + ad.y) : -1e30f;
    float m0 = half_max(e0);
    float m1 = half_max(e1);
    float p0 = __expf(e0 - m0);         // 0 for invalid lanes
    float p1 = __expf(e1 - m1);
    inv0 = 1.f / fmaxf(half_sum(valid ? p0 : 0.f), 1e-16f);
    inv1 = 1.f / fmaxf(half_sum(valid ? p1 : 0.f), 1e-16f);
    gather_pipe8(H16, half_, c8, headsel, sub, s, p0, p1, maxcnt, acc);
  } else {
    // ---- generic path: online softmax over 32-edge chunks per half ----
    float m0 = -1e30f, m1 = -1e30f, s0 = 0.f, s1 = 0.f;
    for (int base = 0; base < maxcnt; base += 32) {
      int j = beg + base + l32;
      bool valid = (base + l32) < cnt;
      int s = valid ? csr[j] : 0;
      float2 as = ((const float2*)a_src)[s];
      float e0 = valid ? lrelu(as.x + ad.x) : -1e30f;
      float e1 = valid ? lrelu(as.y + ad.y) : -1e30f;
      float nm0 = fmaxf(m0, half_max(e0));
      float nm1 = fmaxf(m1, half_max(e1));
      s0 = s0 * __expf(m0 - nm0) + half_sum(valid ? __expf(e0 - nm0) : 0.f);
      s1 = s1 * __expf(m1 - nm1) + half_sum(valid ? __expf(e1 - nm1) : 0.f);
      m0 = nm0; m1 = nm1;
    }
    inv0 = 1.f / fmaxf(s0, 1e-16f);
    inv1 = 1.f / fmaxf(s1, 1e-16f);
    for (int base = 0; base < maxcnt; base += 32) {
      int j = beg + base + l32;
      bool valid = (base + l32) < cnt;
      int s = valid ? csr[j] : 0;
      float2 as = ((const float2*)a_src)[s];
      float e0 = valid ? lrelu(as.x + ad.x) : -1e30f;
      float e1 = valid ? lrelu(as.y + ad.y) : -1e30f;
      float p0 = __expf(e0 - m0);       // 0 invalid
      float p1 = __expf(e1 - m1);
      int rem = maxcnt - base;
      if (rem > 32) rem = 32;
      gather_pipe8(H16, half_, c8, headsel, sub, s, p0, p1, rem, acc);
    }
  }

  // combine edge-of-pair partials: lanes sub=0/1 hold different edge subsets
#pragma unroll
  for (int j = 0; j < 8; ++j) acc[j] += __shfl_xor(acc[j], 16, 64);

  float il = headsel ? inv1 : inv0;
  float v[8], w[8];
#pragma unroll
  for (int j = 0; j < 8; ++j) v[j] = acc[j] * il;
#pragma unroll
  for (int j = 0; j < 8; ++j) w[j] = __shfl_xor(v[j], 8, 64);  // head pair

  if (m < 8 && sub == 0 && live) {
    int cb = m << 1;
    float r[8];
#pragma unroll
    for (int j = 0; j < 8; ++j) {
      int c = ((j & 3) << 4) + cb + (j >> 2);   // true col (head0 decode)
      r[j] = fmaxf(0.5f * (v[j] + w[j]) + bias[c], 0.f);
    }
    if (POOL) {
      float pv = 0.f;
#pragma unroll
      for (int j = 0; j < 8; ++j) {
        int c = ((j & 3) << 4) + cb + (j >> 2);
        pv = fmaf(r[j], lw[c], pv);
      }
      pv += __shfl_xor(pv, 1, 64);
      pv += __shfl_xor(pv, 2, 64);
      pv += __shfl_xor(pv, 4, 64);
      if (m == 0) pvn[dst] = pv;
    } else {
      union { __half2 h2[4]; uint4 u; } pk;
      pk.h2[0] = __floats2half2_rn(r[0], r[1]);
      pk.h2[1] = __floats2half2_rn(r[2], r[3]);
      pk.h2[2] = __floats2half2_rn(r[4], r[5]);
      pk.h2[3] = __floats2half2_rn(r[6], r[7]);
      *(uint4*)(out + (size_t)dst * 64 + m * 8) = pk.u;   // storage s = m*8+j
    }
  }
}

__device__ __forceinline__ int lower_bound(const int* __restrict__ a, int n, int key) {
  int lo = 0, hi = n;
  while (lo < hi) {
    int mid = (lo + hi) >> 1;
    if (a[mid] < key) lo = mid + 1; else hi = mid;
  }
  return lo;
}

__global__ void finalize_kernel(const float* __restrict__ pvn,
                                const int* __restrict__ batch,
                                const float* __restrict__ lb,
                                float* __restrict__ out, int N, int G) {
  int g = blockIdx.x * blockDim.x + threadIdx.x;
  if (g >= G) return;
  int lo = lower_bound(batch, N, g);
  int hi = lower_bound(batch, N, g + 1);
  float s = 0.f;
  for (int i = lo; i < hi; ++i) s += pvn[i];
  out[g] = s / fmaxf((float)(hi - lo), 1.f) + lb[0];
}

extern "C" void kernel_launch(void* const* d_in, const int* in_sizes, int n_in,
                              void* d_out, int out_size, void* d_ws, size_t ws_size,
                              hipStream_t stream) {
  const float* x   = (const float*)d_in[0];
  const int* ei    = (const int*)d_in[1];
  const int* batch = (const int*)d_in[2];
  const float* W1  = (const float*)d_in[3];
  const float* as1 = (const float*)d_in[4];
  const float* ad1 = (const float*)d_in[5];
  const float* b1  = (const float*)d_in[6];
  const float* W2  = (const float*)d_in[7];
  const float* as2 = (const float*)d_in[8];
  const float* ad2 = (const float*)d_in[9];
  const float* b2  = (const float*)d_in[10];
  const float* W3  = (const float*)d_in[11];
  const float* as3 = (const float*)d_in[12];
  const float* ad3 = (const float*)d_in[13];
  const float* b3  = (const float*)d_in[14];
  const float* lw  = (const float*)d_in[15];
  const float* lb  = (const float*)d_in[16];
  float* out = (float*)d_out;

  const int N = in_sizes[0] / 128;   // 50000
  const int E = in_sizes[1] / 2;     // 800000
  const int ET = N + E;              // with self loops
  const int G = out_size;            // 2500
  const int NB = (N + 255) / 256;    // scan blocks (196 <= 256)
  const int EB = (E + 1023) / 1024;  // count_rank blocks

  char* p = (char*)d_ws;
  auto take = [&](size_t bytes) {
    char* r = p;
    p += (bytes + 255) & ~(size_t)255;
    return r;
  };
  int* deg      = (int*)take((size_t)N * 64);    // spread: 1 counter / 64B line
  int* row_ptr  = (int*)take((size_t)(N + 1) * 4);
  int* rank     = (int*)take((size_t)E * 4);
  int* btot     = (int*)take((size_t)NB * 4);
  int* csr      = (int*)take((size_t)ET * 4);
  __half* H16   = (__half*)take((size_t)N * 128 * 2);
  float* a_src  = (float*)take((size_t)N * 2 * 4);
  float* a_dst  = (float*)take((size_t)N * 2 * 4);
  __half* bufA  = (__half*)take((size_t)N * 64 * 2);
  __half* bufB  = (__half*)take((size_t)N * 64 * 2);
  float* pvn    = (float*)take((size_t)N * 4);
  __half* WT1   = (__half*)take((size_t)144 * 128 * 2);
  __half* WT2   = (__half*)take((size_t)144 * 64 * 2);
  __half* WT3   = (__half*)take((size_t)144 * 64 * 2);
  (void)ws_size; (void)n_in;

  // ---- CSR build (dst-grouped, with self loops) + fused weight prep ----
  hipMemsetAsync(deg, 0, (size_t)N * 64, stream);
  count_rank_prep<<<EB + 24, 256, 0, stream>>>(ei, deg, rank, E, EB,
                                               W1, as1, ad1, W2, as2, ad2,
                                               W3, as3, ad3, WT1, WT2, WT3);
  scan_blocks<<<NB, 256, 0, stream>>>(deg, row_ptr, btot, N);
  scan_totals<<<1, 256, 0, stream>>>(btot, NB);
  scan_add<<<NB, 256, 0, stream>>>(row_ptr, csr, btot, N, ET);
  place_kernel<<<EB, 256, 0, stream>>>(ei, rank, row_ptr, csr, E);

  const int gblk = (N + 63) / 64;           // 782
  const int ablk = (N + 7) / 8;             // 8 dsts per block (2 per wave)
  constexpr int LDS1 = (64 + 144) * (128 + 8) * 2;   // 56576 B
  constexpr int LDS2 = (64 + 144) * (64 + 8) * 2;    // 29952 B

  // ---- layer 1 (K=128, fp32 in) ----
  gemm_mfma<128, false><<<gblk, 256, LDS1, stream>>>(x, WT1, H16, a_src, a_dst, N);
  aggregate_fused<0><<<ablk, 256, 0, stream>>>(H16, a_src, a_dst, b1, row_ptr, csr,
                                               bufA, lw, pvn, N);
  // ---- layer 2 (K=64, fp16 in) ----
  gemm_mfma<64, true><<<gblk, 256, LDS2, stream>>>(bufA, WT2, H16, a_src, a_dst, N);
  aggregate_fused<0><<<ablk, 256, 0, stream>>>(H16, a_src, a_dst, b2, row_ptr, csr,
                                               bufB, lw, pvn, N);
  // ---- layer 3 (K=64, fp16 in) + fused pool ----
  gemm_mfma<64, true><<<gblk, 256, LDS2, stream>>>(bufB, WT3, H16, a_src, a_dst, N);
  aggregate_fused<1><<<ablk, 256, 0, stream>>>(H16, a_src, a_dst, b3, row_ptr, csr,
                                               bufA, lw, pvn, N);

  // ---- finalize: per-graph mean + linear ----
  finalize_kernel<<<(G + 255) / 256, 256, 0, stream>>>(pvn, batch, lb, out, N, G);
}